// Round 8
// baseline (33177.179 us; speedup 1.0000x reference)
//
#include <hip/hip_runtime.h>
#include <stdint.h>

#define NB 128   // batch
#define NT 512   // time steps
#define NI 256   // input dim
#define NH 512   // hidden dim
#define NO 256   // output dim

// ---------- bf16 helpers ----------
__device__ __forceinline__ uint16_t f2bf(float x) {
  uint32_t u = __float_as_uint(x);
  return (uint16_t)((u + 0x7fffu + ((u >> 16) & 1u)) >> 16);
}
__device__ __forceinline__ uint32_t pack2bf(float a, float b) {
  return (uint32_t)f2bf(a) | ((uint32_t)f2bf(b) << 16);
}

__device__ __forceinline__ float fast_tanh(float x) {
  float e = __expf(2.0f * x);
#if __has_builtin(__builtin_amdgcn_rcpf)
  return 1.0f - 2.0f * __builtin_amdgcn_rcpf(e + 1.0f);
#else
  return 1.0f - 2.0f / (e + 1.0f);
#endif
}

typedef __bf16 bf16x8 __attribute__((ext_vector_type(8)));
typedef float f32x4 __attribute__((ext_vector_type(4)));

__device__ __forceinline__ f32x4 mfma16(bf16x8 a, uint4 b, f32x4 c) {
  return __builtin_amdgcn_mfma_f32_16x16x32_bf16(a, __builtin_bit_cast(bf16x8, b), c, 0, 0, 0);
}

// ---------- kernel 0: pack W_hh B-frags; Wih->frag order; transpose W_out; bias sum ----------
// B-frag quad q = u*16 + tk (u=n-tile 0..3, tk=k-tile 0..15):
//   n = (t>>6)*64 + u*16 + (t&15), k = tk*32 + ((t>>4)&3)*8 + j, value W_hh[n][k].
// Stored WB[q*512 + t]. recur2 WG kh uses tk in [kh*8, kh*8+8) -> 32 quads, all regs.
__global__ __launch_bounds__(256) void prep_kernel(const float* __restrict__ Whh,
                                                   const float* __restrict__ Wih,
                                                   const float* __restrict__ Wout,
                                                   const float* __restrict__ bih,
                                                   const float* __restrict__ bhh,
                                                   uint4* __restrict__ WB,
                                                   float* __restrict__ WoT,
                                                   uint4* __restrict__ WihF,
                                                   float* __restrict__ BS) {
  int idx = blockIdx.x * 256 + threadIdx.x;
  if (idx < 32768) {                       // W_hh B-fragments
    int q = idx >> 9, t = idx & 511;
    int u = q >> 4, tk = q & 15;
    int n = (t >> 6) * 64 + u * 16 + (t & 15);
    int kb = tk * 32 + ((t >> 4) & 3) * 8;
    const float* row = Whh + (size_t)n * NH + kb;
    float4 f0 = *(const float4*)row;
    float4 f1 = *(const float4*)(row + 4);
    uint4 wq;
    wq.x = pack2bf(f0.x, f0.y);
    wq.y = pack2bf(f0.z, f0.w);
    wq.z = pack2bf(f1.x, f1.y);
    wq.w = pack2bf(f1.z, f1.w);
    WB[idx] = wq;
  } else if (idx < 49152) {                // Wih A-fragments (for xproj arg0)
    int i = idx - 32768;
    int l = i & 63;
    int uk = i >> 6;
    int k0 = uk & 7, u = uk >> 3;
    int n = u * 16 + (l & 15);
    int kb = k0 * 32 + (l >> 4) * 8;
    const float* row = Wih + (size_t)n * NI + kb;
    float4 f0 = *(const float4*)row;
    float4 f1 = *(const float4*)(row + 4);
    uint4 wq;
    wq.x = pack2bf(f0.x, f0.y);
    wq.y = pack2bf(f0.z, f0.w);
    wq.z = pack2bf(f1.x, f1.y);
    wq.w = pack2bf(f1.z, f1.w);
    WihF[i] = wq;
  } else if (idx < 81920) {                // W_out transpose (fp32)
    int i = idx - 49152;
    int o4 = (i & 63) * 4;
    int k = i >> 6;
    float4 v;
    v.x = Wout[(size_t)(o4 + 0) * NH + k];
    v.y = Wout[(size_t)(o4 + 1) * NH + k];
    v.z = Wout[(size_t)(o4 + 2) * NH + k];
    v.w = Wout[(size_t)(o4 + 3) * NH + k];
    *(float4*)&WoT[(size_t)k * NO + o4] = v;
  } else if (idx < 82432) {                // bias sum
    int n = idx - 81920;
    BS[n] = bih[n] + bhh[n];
  }
}

// ---------- kernel 1: x_proj GEMM via bf16 MFMA, frag-swizzled B ----------
__global__ __launch_bounds__(256, 2) void xproj_kernel(const float* __restrict__ A,
                                                       const uint4* __restrict__ WihF,
                                                       const float* __restrict__ BS,
                                                       uint16_t* __restrict__ XP) {
  const int w = threadIdx.x >> 6;
  const int l = threadIdx.x & 63;
  const int sl = l & 15, quad = l >> 4;
  const int m = blockIdx.x * 64 + w * 16 + sl;

  f32x4 acc[32] = {};
  const float* arow = A + (size_t)m * NI;

  for (int k0 = 0; k0 < 8; ++k0) {
    float4 f0 = *(const float4*)(arow + k0 * 32 + quad * 8);
    float4 f1 = *(const float4*)(arow + k0 * 32 + quad * 8 + 4);
    uint4 ap;
    ap.x = pack2bf(f0.x, f0.y);
    ap.y = pack2bf(f0.z, f0.w);
    ap.z = pack2bf(f1.x, f1.y);
    ap.w = pack2bf(f1.z, f1.w);
    bf16x8 afrag = __builtin_bit_cast(bf16x8, ap);
#pragma unroll
    for (int u = 0; u < 32; ++u) {
      uint4 bp = WihF[(u * 8 + k0) * 64 + l];
      acc[u] = __builtin_amdgcn_mfma_f32_16x16x32_bf16(
          __builtin_bit_cast(bf16x8, bp), afrag, acc[u], 0, 0, 0);
    }
  }

  uint16_t* xrow = XP + (size_t)m * NH;
#pragma unroll
  for (int u = 0; u < 32; ++u) {
    float4 bs = *(const float4*)(BS + u * 16 + quad * 4);
    uint2 pw;
    pw.x = pack2bf(acc[u][0] + bs.x, acc[u][1] + bs.y);
    pw.y = pack2bf(acc[u][2] + bs.z, acc[u][3] + bs.w);
    *(uint2*)(xrow + u * 16 + quad * 4) = pw;
  }
}

// ---------- kernel 2: recurrence, 2 WGs per batch (k-split), weights ALL in regs ----------
// 256 WGs x 512 thr, 1 WG/CU (reg-bound). WG = (b = blk>>1, kh = blk&1).
// Per step: 32 MFMAs/wave over k-half; partial y exchanged with partner WG
// through L2/L3 buffer + per-wave release/acquire flags (value = ts+1, so the
// 0xAA ws re-poison can never alias). Parity double-buffer; safety-capped spin.
__global__ __launch_bounds__(512, 2) void recur2_kernel(const uint4* __restrict__ WB,
                                                        const float* __restrict__ WoT,
                                                        const uint16_t* __restrict__ XP,
                                                        const float* __restrict__ h0,
                                                        const float* __restrict__ bout,
                                                        float* __restrict__ out,
                                                        float* __restrict__ yp,
                                                        unsigned* __restrict__ flags) {
  __shared__ __align__(16) uint16_t h2[2][NH];   // bf16 h, double-buffered
  __shared__ float hsf[NH];                      // fp32 h for readout
  const int t = threadIdx.x;
  const int w = t >> 6;
  const int quad = (t >> 4) & 3;
  const int kh = blockIdx.x & 1;
  const int b = blockIdx.x >> 1;
  const float invT = 1.0f / (float)NT;

  // 32 B-frag quads, all register-resident (128 VGPRs)
  uint4 Wr[32];
#pragma unroll
  for (int u = 0; u < 4; ++u)
#pragma unroll
    for (int tkl = 0; tkl < 8; ++tkl)
      Wr[u * 8 + tkl] = WB[(size_t)(u * 16 + kh * 8 + tkl) * 512 + t];

  float hj = h0[t];
  h2[0][t] = f2bf(hj);
  __syncthreads();

  const uint16_t* xpb = XP + (size_t)b * NT * NH + t;
  float xpv = __uint_as_float((uint32_t)xpb[0] << 16);

  float* yp_me = yp + (size_t)blockIdx.x * 2 * NH;
  const float* yp_pa = yp + (size_t)(blockIdx.x ^ 1) * 2 * NH;
  volatile unsigned* fl_me = flags + blockIdx.x * 8;
  volatile const unsigned* fl_pa = flags + (blockIdx.x ^ 1) * 8;

  for (int ts = 0; ts < NT; ++ts) {
    const int cur = ts & 1;
    // prefetch next step's xp (streaming, known address)
    int tsn = (ts + 1 < NT) ? ts + 1 : ts;
    float xpn = __uint_as_float((uint32_t)xpb[(size_t)tsn * NH] << 16);

    const uint16_t* hbuf = h2[cur] + kh * 256;
    f32x4 a0 = {}, a1 = {}, a2 = {}, a3 = {};
#pragma unroll
    for (int tkl = 0; tkl < 8; ++tkl) {
      bf16x8 hf = *(const bf16x8*)(hbuf + tkl * 32 + quad * 8);
      a0 = mfma16(hf, Wr[tkl], a0);
      a1 = mfma16(hf, Wr[8 + tkl], a1);
      a2 = mfma16(hf, Wr[16 + tkl], a2);
      a3 = mfma16(hf, Wr[24 + tkl], a3);
    }
    float ypv = (quad == 0) ? a0[0] : (quad == 1) ? a1[0] : (quad == 2) ? a2[0] : a3[0];

    yp_me[cur * NH + t] = ypv;        // coalesced (myn == t)
    __threadfence();                  // wave-level vmcnt drain + device visibility
    if ((t & 63) == 0) fl_me[w] = (unsigned)(ts + 1);   // release

    // acquire partner's wave-w partials
    unsigned want = (unsigned)(ts + 1);
    int guard = 0;
    while (fl_pa[w] != want && guard < (1 << 16)) ++guard;
    __threadfence();
    float yo = yp_pa[cur * NH + t];

    float hnew = fmaf(fast_tanh(xpv + ypv + yo), invT, hj);
    hj = hnew;
    h2[cur ^ 1][t] = f2bf(hnew);
    xpv = xpn;
    __syncthreads();                  // publish h for next step
  }

  hsf[t] = hj;
  __syncthreads();

  // readout split across the pair: WG kh writes o in [kh*128, kh*128+128)
  if (t < 128) {
    int o = kh * 128 + t;
    float c0 = 0.f, c1 = 0.f;
#pragma unroll 4
    for (int k = 0; k < NH; k += 2) {
      c0 = fmaf(WoT[(size_t)k * NO + o], hsf[k], c0);
      c1 = fmaf(WoT[(size_t)(k + 1) * NO + o], hsf[k + 1], c1);
    }
    out[(size_t)b * NO + o] = c0 + c1 + bout[o];
  }
}

// ---------- launch ----------
extern "C" void kernel_launch(void* const* d_in, const int* in_sizes, int n_in,
                              void* d_out, int out_size, void* d_ws, size_t ws_size,
                              hipStream_t stream) {
  const float* inputs = (const float*)d_in[0];
  const float* Wih    = (const float*)d_in[1];
  const float* bih    = (const float*)d_in[2];
  const float* Whh    = (const float*)d_in[3];
  const float* bhh    = (const float*)d_in[4];
  const float* Wout   = (const float*)d_in[5];
  const float* bout   = (const float*)d_in[6];
  const float* h0     = (const float*)d_in[7];
  float* out = (float*)d_out;

  char* ws = (char*)d_ws;
  uint4*    WB    = (uint4*)ws;                          // 512 KB: W_hh B-frags
  float*    WoT   = (float*)(ws + (512u << 10));         // 512 KB: W_out^T
  uint4*    WihF  = (uint4*)(ws + (1024u << 10));        // 256 KB: Wih A-frags
  float*    BS    = (float*)(ws + (1280u << 10));        // 2 KB: bias sum
  uint16_t* XP    = (uint16_t*)(ws + (1536u << 10));     // 64 MB: x_proj bf16
  char*     ws2   = ws + (1536u << 10) + ((size_t)NB * NT * NH * 2);
  float*    YP    = (float*)ws2;                         // 1 MB: partial-y exchange
  unsigned* FLAGS = (unsigned*)(ws2 + (1u << 20));       // 8 KB: per-wave flags

  hipLaunchKernelGGL(prep_kernel, dim3(322), dim3(256), 0, stream,
                     Whh, Wih, Wout, bih, bhh, WB, WoT, WihF, BS);
  hipLaunchKernelGGL(xproj_kernel, dim3(NB * NT / 64), dim3(256), 0, stream,
                     inputs, WihF, BS, XP);
  hipLaunchKernelGGL(recur2_kernel, dim3(NB * 2), dim3(512), 0, stream,
                     WB, WoT, XP, h0, bout, out, YP, FLAGS);
}

// Round 9
// 929.902 us; speedup vs baseline: 35.6781x; 35.6781x over previous
//
#include <hip/hip_runtime.h>
#include <stdint.h>

#define NB 128   // batch
#define NT 512   // time steps
#define NI 256   // input dim
#define NH 512   // hidden dim
#define NO 256   // output dim

// ---------- bf16 helpers ----------
__device__ __forceinline__ uint16_t f2bf(float x) {
  uint32_t u = __float_as_uint(x);
  return (uint16_t)((u + 0x7fffu + ((u >> 16) & 1u)) >> 16);
}
__device__ __forceinline__ uint32_t pack2bf(float a, float b) {
  return (uint32_t)f2bf(a) | ((uint32_t)f2bf(b) << 16);
}

__device__ __forceinline__ float fast_tanh(float x) {
  float e = __expf(2.0f * x);
#if __has_builtin(__builtin_amdgcn_rcpf)
  return 1.0f - 2.0f * __builtin_amdgcn_rcpf(e + 1.0f);
#else
  return 1.0f - 2.0f / (e + 1.0f);
#endif
}

typedef __bf16 bf16x8 __attribute__((ext_vector_type(8)));
typedef float f32x4 __attribute__((ext_vector_type(4)));

__device__ __forceinline__ f32x4 mfma16(bf16x8 a, uint4 b, f32x4 c) {
  return __builtin_amdgcn_mfma_f32_16x16x32_bf16(a, __builtin_bit_cast(bf16x8, b), c, 0, 0, 0);
}
__device__ __forceinline__ f32x4 mfma16_ab(uint4 a, bf16x8 b, f32x4 c) {
  return __builtin_amdgcn_mfma_f32_16x16x32_bf16(__builtin_bit_cast(bf16x8, a), b, c, 0, 0, 0);
}

// ---------- kernel 0: pack W_hh B-frags; Wih->frag order; transpose W_out; bias sum ----------
// B-frag quad q = u*16 + tk (u=n-tile 0..3, tk=k-tile 0..15):
//   n = (t>>6)*64 + u*16 + (t&15), k = tk*32 + ((t>>4)&3)*8 + j, value W_hh[n][k].
// Stored WB[q*512 + t]. q<52 -> regs, q>=52 -> LDS in recur.
// xproj A-frag WihF[(U*8+k0)*64 + l]: row n=U*16+(l&15), k=k0*32+(l>>4)*8+j.
__global__ __launch_bounds__(256) void prep_kernel(const float* __restrict__ Whh,
                                                   const float* __restrict__ Wih,
                                                   const float* __restrict__ Wout,
                                                   const float* __restrict__ bih,
                                                   const float* __restrict__ bhh,
                                                   uint4* __restrict__ WB,
                                                   float* __restrict__ WoT,
                                                   uint4* __restrict__ WihF,
                                                   float* __restrict__ BS) {
  int idx = blockIdx.x * 256 + threadIdx.x;
  if (idx < 32768) {                       // W_hh B-fragments
    int q = idx >> 9, t = idx & 511;
    int u = q >> 4, tk = q & 15;
    int n = (t >> 6) * 64 + u * 16 + (t & 15);
    int kb = tk * 32 + ((t >> 4) & 3) * 8;
    const float* row = Whh + (size_t)n * NH + kb;
    float4 f0 = *(const float4*)row;
    float4 f1 = *(const float4*)(row + 4);
    uint4 wq;
    wq.x = pack2bf(f0.x, f0.y);
    wq.y = pack2bf(f0.z, f0.w);
    wq.z = pack2bf(f1.x, f1.y);
    wq.w = pack2bf(f1.z, f1.w);
    WB[idx] = wq;
  } else if (idx < 49152) {                // Wih A-fragments (for xproj arg0)
    int i = idx - 32768;
    int l = i & 63;
    int uk = i >> 6;
    int k0 = uk & 7, u = uk >> 3;
    int n = u * 16 + (l & 15);
    int kb = k0 * 32 + (l >> 4) * 8;
    const float* row = Wih + (size_t)n * NI + kb;
    float4 f0 = *(const float4*)row;
    float4 f1 = *(const float4*)(row + 4);
    uint4 wq;
    wq.x = pack2bf(f0.x, f0.y);
    wq.y = pack2bf(f0.z, f0.w);
    wq.z = pack2bf(f1.x, f1.y);
    wq.w = pack2bf(f1.z, f1.w);
    WihF[i] = wq;
  } else if (idx < 81920) {                // W_out transpose (fp32)
    int i = idx - 49152;
    int o4 = (i & 63) * 4;
    int k = i >> 6;
    float4 v;
    v.x = Wout[(size_t)(o4 + 0) * NH + k];
    v.y = Wout[(size_t)(o4 + 1) * NH + k];
    v.z = Wout[(size_t)(o4 + 2) * NH + k];
    v.w = Wout[(size_t)(o4 + 3) * NH + k];
    *(float4*)&WoT[(size_t)k * NO + o4] = v;
  } else if (idx < 82432) {                // bias sum
    int n = idx - 81920;
    BS[n] = bih[n] + bhh[n];
  }
}

// ---------- kernel 1: x_proj GEMM, B register-stationary with m-reuse ----------
// Grid (256 m-chunks, 8 n-groups). WG = 256 thr = 4 waves. Wave w: n-group g
// (4 n-tiles, B = 32 quads in regs, loaded ONCE), m-tiles mt0..mt0+3 with
// double-buffered packed A-frags. Same-m n-groups are 256 blocks apart ->
// same XCD under round-robin -> A re-reads are XCD-L2 hits (perf-only).
__device__ __forceinline__ void ld_pack(uint4 (&af)[8], const float* __restrict__ A,
                                        int mt, int sl, int quad) {
  const float* ar = A + (size_t)(mt * 16 + sl) * NI + quad * 8;
#pragma unroll
  for (int k0 = 0; k0 < 8; ++k0) {
    float4 f0 = *(const float4*)(ar + k0 * 32);
    float4 f1 = *(const float4*)(ar + k0 * 32 + 4);
    uint4 ap;
    ap.x = pack2bf(f0.x, f0.y);
    ap.y = pack2bf(f0.z, f0.w);
    ap.z = pack2bf(f1.x, f1.y);
    ap.w = pack2bf(f1.z, f1.w);
    af[k0] = ap;
  }
}

__device__ __forceinline__ void do_tile(const uint4 (&af)[8], const uint4 (&Wb)[32],
                                        const float4 (&bs)[4], uint16_t* __restrict__ XP,
                                        int g, int mt, int sl, int quad) {
  f32x4 acc[4] = {};
#pragma unroll
  for (int k0 = 0; k0 < 8; ++k0) {
    bf16x8 a = __builtin_bit_cast(bf16x8, af[k0]);
#pragma unroll
    for (int u = 0; u < 4; ++u) acc[u] = mfma16_ab(Wb[u * 8 + k0], a, acc[u]);
  }
  uint16_t* xrow = XP + (size_t)(mt * 16 + sl) * NH + g * 64 + quad * 4;
#pragma unroll
  for (int u = 0; u < 4; ++u) {
    uint2 pw;
    pw.x = pack2bf(acc[u][0] + bs[u].x, acc[u][1] + bs[u].y);
    pw.y = pack2bf(acc[u][2] + bs[u].z, acc[u][3] + bs[u].w);
    *(uint2*)(xrow + u * 16) = pw;
  }
}

__global__ __launch_bounds__(256, 2) void xproj_kernel(const float* __restrict__ A,
                                                       const uint4* __restrict__ WihF,
                                                       const float* __restrict__ BS,
                                                       uint16_t* __restrict__ XP) {
  const int w = threadIdx.x >> 6;
  const int l = threadIdx.x & 63;
  const int sl = l & 15, quad = l >> 4;
  const int g = blockIdx.y;                     // n-group 0..7 (64 cols)
  const int mt0 = blockIdx.x * 16 + w * 4;      // first of 4 m-tiles for this wave

  uint4 Wb[32];                                 // B-frags, loaded once
#pragma unroll
  for (int u = 0; u < 4; ++u)
#pragma unroll
    for (int k0 = 0; k0 < 8; ++k0)
      Wb[u * 8 + k0] = WihF[(size_t)((g * 4 + u) * 8 + k0) * 64 + l];

  float4 bs[4];
#pragma unroll
  for (int u = 0; u < 4; ++u) bs[u] = *(const float4*)(BS + (g * 4 + u) * 16 + quad * 4);

  uint4 afA[8], afB[8];
  ld_pack(afA, A, mt0 + 0, sl, quad);
  ld_pack(afB, A, mt0 + 1, sl, quad);
  do_tile(afA, Wb, bs, XP, g, mt0 + 0, sl, quad);
  ld_pack(afA, A, mt0 + 2, sl, quad);
  do_tile(afB, Wb, bs, XP, g, mt0 + 1, sl, quad);
  ld_pack(afB, A, mt0 + 3, sl, quad);
  do_tile(afA, Wb, bs, XP, g, mt0 + 2, sl, quad);
  do_tile(afB, Wb, bs, XP, g, mt0 + 3, sl, quad);
}

// ---------- kernel 2: recurrence via MFMA (A-replication), 1 barrier/step ----------
// (exact R7 kernel — 781 us known-good)
__global__ __launch_bounds__(512, 2) void recur_kernel(const uint4* __restrict__ WB,
                                                       const float* __restrict__ WoT,
                                                       const uint16_t* __restrict__ XP,
                                                       const float* __restrict__ h0,
                                                       const float* __restrict__ bout,
                                                       float* __restrict__ out) {
  __shared__ uint4 WL[12][512];                  // 96 KB: quads q=52..63
  __shared__ __align__(16) uint16_t h2[2][NH];   // 2 KB: bf16 h, double-buffered
  __shared__ float hsf[NH];                      // 2 KB: fp32 h for readout
  const int t = threadIdx.x;
  const int b = blockIdx.x;
  const int w = t >> 6;
  const int sl = t & 15, quad = (t >> 4) & 3;
  const int myn = w * 64 + quad * 16 + sl;       // h element this lane owns
  const float invT = 1.0f / (float)NT;

  uint4 Wr[52];
#pragma unroll
  for (int q = 0; q < 52; ++q) Wr[q] = WB[q * 512 + t];
#pragma unroll
  for (int i = 0; i < 12; ++i) WL[i][t] = WB[(52 + i) * 512 + t];

  float hj = h0[myn];
  h2[0][myn] = f2bf(hj);
  __syncthreads();

  const uint16_t* xpb = XP + (size_t)b * NT * NH + myn;

  for (int ts = 0; ts < NT; ++ts) {
    const int cur = ts & 1;
    float xpj = __uint_as_float((uint32_t)xpb[(size_t)ts * NH] << 16);

    const uint16_t* hbuf = h2[cur];
    f32x4 acc0 = {}, acc1 = {}, acc2 = {}, acc3 = {};
#pragma unroll
    for (int tk = 0; tk < 16; ++tk) {
      bf16x8 hfrag = *(const bf16x8*)(hbuf + tk * 32 + quad * 8);  // quad-broadcast
      acc0 = mfma16(hfrag, Wr[tk], acc0);
      acc1 = mfma16(hfrag, Wr[16 + tk], acc1);
      acc2 = mfma16(hfrag, Wr[32 + tk], acc2);
      uint4 w3 = (tk < 4) ? Wr[48 + tk] : WL[tk - 4][t];
      acc3 = mfma16(hfrag, w3, acc3);
    }
    float y = (quad == 0) ? acc0[0] : (quad == 1) ? acc1[0] : (quad == 2) ? acc2[0] : acc3[0];
    float hnew = fmaf(fast_tanh(xpj + y), invT, hj);
    hj = hnew;
    h2[cur ^ 1][myn] = f2bf(hnew);
    __syncthreads();
  }

  hsf[myn] = hj;
  __syncthreads();

  if (t < NO) {
    float c0 = 0.f, c1 = 0.f;
#pragma unroll 4
    for (int k = 0; k < NH; k += 2) {
      c0 = fmaf(WoT[(size_t)k * NO + t], hsf[k], c0);
      c1 = fmaf(WoT[(size_t)(k + 1) * NO + t], hsf[k + 1], c1);
    }
    out[(size_t)b * NO + t] = c0 + c1 + bout[t];
  }
}

// ---------- launch ----------
extern "C" void kernel_launch(void* const* d_in, const int* in_sizes, int n_in,
                              void* d_out, int out_size, void* d_ws, size_t ws_size,
                              hipStream_t stream) {
  const float* inputs = (const float*)d_in[0];
  const float* Wih    = (const float*)d_in[1];
  const float* bih    = (const float*)d_in[2];
  const float* Whh    = (const float*)d_in[3];
  const float* bhh    = (const float*)d_in[4];
  const float* Wout   = (const float*)d_in[5];
  const float* bout   = (const float*)d_in[6];
  const float* h0     = (const float*)d_in[7];
  float* out = (float*)d_out;

  char* ws = (char*)d_ws;
  uint4*    WB   = (uint4*)ws;                          // 512 KB: W_hh B-frags
  float*    WoT  = (float*)(ws + (512u << 10));         // 512 KB: W_out^T
  uint4*    WihF = (uint4*)(ws + (1024u << 10));        // 256 KB: Wih A-frags
  float*    BS   = (float*)(ws + (1280u << 10));        // 2 KB: bias sum
  uint16_t* XP   = (uint16_t*)(ws + (1536u << 10));     // 64 MB: x_proj bf16

  hipLaunchKernelGGL(prep_kernel, dim3(322), dim3(256), 0, stream,
                     Whh, Wih, Wout, bih, bhh, WB, WoT, WihF, BS);
  hipLaunchKernelGGL(xproj_kernel, dim3(NB * NT / 256, 8), dim3(256), 0, stream,
                     inputs, WihF, BS, XP);
  hipLaunchKernelGGL(recur_kernel, dim3(NB), dim3(512), 0, stream,
                     WB, WoT, XP, h0, bout, out);
}